// Round 1
// baseline (973.760 us; speedup 1.0000x reference)
//
#include <hip/hip_runtime.h>

#define ND 48      // feature dim
#define NQ 12      // float4s per row (48/4)
#define KSTEPS 10
#define ALPHA 0.1f
#define SCAN_BS 512

// ---- degree count ----
__global__ void deg_kernel(const int* __restrict__ src, const int* __restrict__ dst,
                           int* __restrict__ outdeg, int* __restrict__ indeg, int E) {
    int i = blockIdx.x * blockDim.x + threadIdx.x;
    int stride = gridDim.x * blockDim.x;
    for (; i < E; i += stride) {
        atomicAdd(&outdeg[src[i]], 1);
        atomicAdd(&indeg[dst[i]], 1);
    }
}

// ---- per-chunk inclusive scan (Hillis-Steele, 512 elems/block) ----
__global__ void scan_chunks(const int* __restrict__ deg, int* __restrict__ incl,
                            int* __restrict__ bsum, int n) {
    __shared__ int sm[SCAN_BS];
    int tid = threadIdx.x;
    int i = blockIdx.x * SCAN_BS + tid;
    int v = (i < n) ? deg[i] : 0;
    sm[tid] = v;
    __syncthreads();
    for (int off = 1; off < SCAN_BS; off <<= 1) {
        int t = (tid >= off) ? sm[tid - off] : 0;
        __syncthreads();
        sm[tid] += t;
        __syncthreads();
    }
    if (i < n) incl[i] = sm[tid];
    if (tid == SCAN_BS - 1) bsum[blockIdx.x] = sm[tid];
}

// ---- scan of block sums (exclusive, in place); nb <= 256 ----
__global__ void scan_sums(int* __restrict__ bsum, int nb) {
    __shared__ int sm[256];
    int tid = threadIdx.x;
    int v = (tid < nb) ? bsum[tid] : 0;
    sm[tid] = v;
    __syncthreads();
    for (int off = 1; off < 256; off <<= 1) {
        int t = (tid >= off) ? sm[tid - off] : 0;
        __syncthreads();
        sm[tid] += t;
        __syncthreads();
    }
    if (tid < nb) bsum[tid] = sm[tid] - v;   // exclusive
}

// ---- row_start/cursor + norms ----
__global__ void finalize_kernel(const int* __restrict__ incl, const int* __restrict__ boff,
                                const int* __restrict__ indeg, const int* __restrict__ outdeg,
                                int* __restrict__ row_start, int* __restrict__ cursor,
                                float* __restrict__ snorm, float* __restrict__ dnorm09, int n) {
    int i = blockIdx.x * blockDim.x + threadIdx.x;
    if (i >= n) return;
    int rs = boff[i >> 9] + incl[i] - indeg[i];   // global exclusive prefix
    row_start[i] = rs;
    cursor[i] = rs;
    int od = outdeg[i]; if (od < 1) od = 1;
    int id = indeg[i];  if (id < 1) id = 1;
    snorm[i]   = rsqrtf((float)od);
    dnorm09[i] = (1.0f - ALPHA) * rsqrtf((float)id);
}

// ---- CSR fill (col[] = src ids grouped by dst) ----
__global__ void fill_kernel(const int* __restrict__ src, const int* __restrict__ dst,
                            int* __restrict__ cursor, int* __restrict__ col, int E) {
    int i = blockIdx.x * blockDim.x + threadIdx.x;
    int stride = gridDim.x * blockDim.x;
    for (; i < E; i += stride) {
        int p = atomicAdd(&cursor[dst[i]], 1);
        col[p] = src[i];
    }
}

// ---- feat_s0 = features * snorm ----
__global__ void init_kernel(const float4* __restrict__ feat0, const float* __restrict__ snorm,
                            float4* __restrict__ out, int nq /* N*NQ */) {
    int i = blockIdx.x * blockDim.x + threadIdx.x;
    if (i >= nq) return;
    int node = i / NQ;
    float s = snorm[node];
    float4 v = feat0[i];
    v.x *= s; v.y *= s; v.z *= s; v.w *= s;
    out[i] = v;
}

// ---- one propagation step, fused gather+combine ----
// fin holds feat_s (pre-scaled by snorm). Writes feat_{k+1}*snorm (or unscaled if last).
__global__ __launch_bounds__(256) void step_kernel(
        const float4* __restrict__ fin, const float4* __restrict__ feat0,
        const int* __restrict__ row_start, const int* __restrict__ indeg,
        const int* __restrict__ col, const float* __restrict__ snorm,
        const float* __restrict__ dnorm09, float4* __restrict__ fout,
        int n /* N */, int last) {
    int tid = blockIdx.x * blockDim.x + threadIdx.x;
    if (tid >= n * NQ) return;
    int node = tid / NQ;
    int q = tid - node * NQ;
    int rs = row_start[node];
    int de = indeg[node];
    float ax = 0.f, ay = 0.f, az = 0.f, aw = 0.f;
    for (int j = 0; j < de; ++j) {
        int s = col[rs + j];               // broadcast across the node's 12 lanes
        float4 v = fin[s * NQ + q];        // 192B contiguous per node-group
        ax += v.x; ay += v.y; az += v.z; aw += v.w;
    }
    float dn = dnorm09[node];
    float4 f0 = feat0[tid];
    float4 r;
    r.x = ax * dn + ALPHA * f0.x;
    r.y = ay * dn + ALPHA * f0.y;
    r.z = az * dn + ALPHA * f0.z;
    r.w = aw * dn + ALPHA * f0.w;
    if (!last) {
        float sn = snorm[node];
        r.x *= sn; r.y *= sn; r.z *= sn; r.w *= sn;
    }
    fout[tid] = r;
}

extern "C" void kernel_launch(void* const* d_in, const int* in_sizes, int n_in,
                              void* d_out, int out_size, void* d_ws, size_t ws_size,
                              hipStream_t stream) {
    const float* features = (const float*)d_in[0];
    const int*   src      = (const int*)d_in[1];
    const int*   dst      = (const int*)d_in[2];
    float*       out      = (float*)d_out;

    const int N = in_sizes[0] / ND;
    const int E = in_sizes[1];
    const int nb1 = (N + SCAN_BS - 1) / SCAN_BS;   // 196 for N=100000

    // ---- workspace layout (256B-aligned slices) ----
    char* w = (char*)d_ws;
    auto alloc = [&](size_t bytes) -> void* {
        void* p = (void*)w;
        w += (bytes + 255) & ~(size_t)255;
        return p;
    };
    float4* featA   = (float4*)alloc((size_t)N * ND * sizeof(float));
    int* col        = (int*)alloc((size_t)E * sizeof(int));
    int* indeg      = (int*)alloc((size_t)N * sizeof(int));
    int* outdeg     = (int*)alloc((size_t)N * sizeof(int));
    int* row_start  = (int*)alloc((size_t)N * sizeof(int));
    int* cursor     = (int*)alloc((size_t)N * sizeof(int));
    float* snorm    = (float*)alloc((size_t)N * sizeof(float));
    float* dnorm09  = (float*)alloc((size_t)N * sizeof(float));
    int* incl       = (int*)alloc((size_t)N * sizeof(int));
    int* bsum       = (int*)alloc((size_t)nb1 * sizeof(int));

    // ---- zero degree counters ----
    hipMemsetAsync(indeg, 0, (size_t)N * sizeof(int), stream);
    hipMemsetAsync(outdeg, 0, (size_t)N * sizeof(int), stream);

    const int gridE = (E + 255) / 256;
    const int gridN = (N + 255) / 256;
    const int nq = N * NQ;
    const int gridNQ = (nq + 255) / 256;

    deg_kernel<<<gridE, 256, 0, stream>>>(src, dst, outdeg, indeg, E);
    scan_chunks<<<nb1, SCAN_BS, 0, stream>>>(indeg, incl, bsum, N);
    scan_sums<<<1, 256, 0, stream>>>(bsum, nb1);
    finalize_kernel<<<gridN, 256, 0, stream>>>(incl, bsum, indeg, outdeg,
                                               row_start, cursor, snorm, dnorm09, N);
    fill_kernel<<<gridE, 256, 0, stream>>>(src, dst, cursor, col, E);

    // ---- propagation: ping-pong between d_out (Y) and featA (X) ----
    float4* X = featA;
    float4* Y = (float4*)out;
    init_kernel<<<gridNQ, 256, 0, stream>>>((const float4*)features, snorm, Y, nq);
    for (int k = 0; k < KSTEPS; ++k) {
        const float4* fin = (k & 1) ? (const float4*)X : (const float4*)Y;
        float4*       fo  = (k & 1) ? Y : X;
        int last = (k == KSTEPS - 1);
        step_kernel<<<gridNQ, 256, 0, stream>>>(fin, (const float4*)features,
                                                row_start, indeg, col, snorm,
                                                dnorm09, fo, N, last);
    }
    // k=9 (odd) writes into Y == d_out with last=1 (unscaled). Done.
}

// Round 2
// 753.180 us; speedup vs baseline: 1.2929x; 1.2929x over previous
//
#include <hip/hip_runtime.h>
#include <hip/hip_fp16.h>

#define ND 48      // feature dim (floats)
#define NH 6       // uint4 (8 halves) chunks per row (48/8)
#define KSTEPS 10
#define ALPHA 0.1f
#define SCAN_BS 512

// ---- fp16 pack/unpack helpers ----
__device__ inline float2 unpack2(unsigned int u) {
    __half2 h;
    *reinterpret_cast<unsigned int*>(&h) = u;
    return __half22float2(h);
}
__device__ inline unsigned int pack2(float x, float y) {
    __half2 h = __floats2half2_rn(x, y);
    return *reinterpret_cast<unsigned int*>(&h);
}
__device__ inline void add8(float* a, uint4 v) {
    float2 t;
    t = unpack2(v.x); a[0] += t.x; a[1] += t.y;
    t = unpack2(v.y); a[2] += t.x; a[3] += t.y;
    t = unpack2(v.z); a[4] += t.x; a[5] += t.y;
    t = unpack2(v.w); a[6] += t.x; a[7] += t.y;
}

// ---- degree count ----
__global__ void deg_kernel(const int* __restrict__ src, const int* __restrict__ dst,
                           int* __restrict__ outdeg, int* __restrict__ indeg, int E) {
    int i = blockIdx.x * blockDim.x + threadIdx.x;
    int stride = gridDim.x * blockDim.x;
    for (; i < E; i += stride) {
        atomicAdd(&outdeg[src[i]], 1);
        atomicAdd(&indeg[dst[i]], 1);
    }
}

// ---- per-chunk inclusive scan (512 elems/block) ----
__global__ void scan_chunks(const int* __restrict__ deg, int* __restrict__ incl,
                            int* __restrict__ bsum, int n) {
    __shared__ int sm[SCAN_BS];
    int tid = threadIdx.x;
    int i = blockIdx.x * SCAN_BS + tid;
    int v = (i < n) ? deg[i] : 0;
    sm[tid] = v;
    __syncthreads();
    for (int off = 1; off < SCAN_BS; off <<= 1) {
        int t = (tid >= off) ? sm[tid - off] : 0;
        __syncthreads();
        sm[tid] += t;
        __syncthreads();
    }
    if (i < n) incl[i] = sm[tid];
    if (tid == SCAN_BS - 1) bsum[blockIdx.x] = sm[tid];
}

// ---- scan of block sums (exclusive, in place); nb <= 256 ----
__global__ void scan_sums(int* __restrict__ bsum, int nb) {
    __shared__ int sm[256];
    int tid = threadIdx.x;
    int v = (tid < nb) ? bsum[tid] : 0;
    sm[tid] = v;
    __syncthreads();
    for (int off = 1; off < 256; off <<= 1) {
        int t = (tid >= off) ? sm[tid - off] : 0;
        __syncthreads();
        sm[tid] += t;
        __syncthreads();
    }
    if (tid < nb) bsum[tid] = sm[tid] - v;   // exclusive
}

// ---- row_start/cursor + norms ----
__global__ void finalize_kernel(const int* __restrict__ incl, const int* __restrict__ boff,
                                const int* __restrict__ indeg, const int* __restrict__ outdeg,
                                int* __restrict__ row_start, int* __restrict__ cursor,
                                float* __restrict__ snorm, float* __restrict__ dnorm09, int n) {
    int i = blockIdx.x * blockDim.x + threadIdx.x;
    if (i >= n) return;
    int rs = boff[i >> 9] + incl[i] - indeg[i];   // global exclusive prefix
    row_start[i] = rs;
    cursor[i] = rs;
    int od = outdeg[i]; if (od < 1) od = 1;
    int id = indeg[i];  if (id < 1) id = 1;
    snorm[i]   = rsqrtf((float)od);
    dnorm09[i] = (1.0f - ALPHA) * rsqrtf((float)id);
}

// ---- CSR fill (col[] = src ids grouped by dst) ----
__global__ void fill_kernel(const int* __restrict__ src, const int* __restrict__ dst,
                            int* __restrict__ cursor, int* __restrict__ col, int E) {
    int i = blockIdx.x * blockDim.x + threadIdx.x;
    int stride = gridDim.x * blockDim.x;
    for (; i < E; i += stride) {
        int p = atomicAdd(&cursor[dst[i]], 1);
        col[p] = src[i];
    }
}

// ---- featH0 = fp16(features * snorm) ----
__global__ void init_kernel(const float4* __restrict__ feat0, const float* __restrict__ snorm,
                            uint4* __restrict__ featH, int total /* N*NH */) {
    int i = blockIdx.x * blockDim.x + threadIdx.x;
    if (i >= total) return;
    int node = i / NH;
    float s = snorm[node];
    float4 a = feat0[i * 2];
    float4 b = feat0[i * 2 + 1];
    uint4 o;
    o.x = pack2(a.x * s, a.y * s);
    o.y = pack2(a.z * s, a.w * s);
    o.z = pack2(b.x * s, b.y * s);
    o.w = pack2(b.z * s, b.w * s);
    featH[i] = o;
}

// ---- one propagation step, fused gather+combine (fp16 storage, f32 accum) ----
template <int LAST>
__global__ __launch_bounds__(256) void step_kernel(
        const uint4* __restrict__ fin, const float4* __restrict__ feat0,
        const int* __restrict__ row_start, const int* __restrict__ indeg,
        const int* __restrict__ col, const float* __restrict__ snorm,
        const float* __restrict__ dnorm09,
        uint4* __restrict__ fout, float4* __restrict__ foutF, int n /* N */) {
    int tid = blockIdx.x * blockDim.x + threadIdx.x;
    if (tid >= n * NH) return;
    int node = tid / NH;
    int q = tid - node * NH;
    int rs = row_start[node];
    int de = indeg[node];
    float acc[8] = {0.f, 0.f, 0.f, 0.f, 0.f, 0.f, 0.f, 0.f};
    int j = 0;
    for (; j + 2 <= de; j += 2) {
        int s0 = col[rs + j];
        int s1 = col[rs + j + 1];
        uint4 v0 = fin[s0 * NH + q];
        uint4 v1 = fin[s1 * NH + q];
        add8(acc, v0);
        add8(acc, v1);
    }
    if (j < de) {
        int s0 = col[rs + j];
        add8(acc, fin[s0 * NH + q]);
    }
    float dn = dnorm09[node];
    float4 f0a = feat0[tid * 2];
    float4 f0b = feat0[tid * 2 + 1];
    float r[8];
    r[0] = acc[0] * dn + ALPHA * f0a.x;
    r[1] = acc[1] * dn + ALPHA * f0a.y;
    r[2] = acc[2] * dn + ALPHA * f0a.z;
    r[3] = acc[3] * dn + ALPHA * f0a.w;
    r[4] = acc[4] * dn + ALPHA * f0b.x;
    r[5] = acc[5] * dn + ALPHA * f0b.y;
    r[6] = acc[6] * dn + ALPHA * f0b.z;
    r[7] = acc[7] * dn + ALPHA * f0b.w;
    if (LAST) {
        float4 oa, ob;
        oa.x = r[0]; oa.y = r[1]; oa.z = r[2]; oa.w = r[3];
        ob.x = r[4]; ob.y = r[5]; ob.z = r[6]; ob.w = r[7];
        foutF[tid * 2]     = oa;
        foutF[tid * 2 + 1] = ob;
    } else {
        float sn = snorm[node];
        uint4 o;
        o.x = pack2(r[0] * sn, r[1] * sn);
        o.y = pack2(r[2] * sn, r[3] * sn);
        o.z = pack2(r[4] * sn, r[5] * sn);
        o.w = pack2(r[6] * sn, r[7] * sn);
        fout[tid] = o;
    }
}

extern "C" void kernel_launch(void* const* d_in, const int* in_sizes, int n_in,
                              void* d_out, int out_size, void* d_ws, size_t ws_size,
                              hipStream_t stream) {
    const float* features = (const float*)d_in[0];
    const int*   src      = (const int*)d_in[1];
    const int*   dst      = (const int*)d_in[2];
    float*       out      = (float*)d_out;

    const int N = in_sizes[0] / ND;
    const int E = in_sizes[1];
    const int nb1 = (N + SCAN_BS - 1) / SCAN_BS;

    // ---- workspace layout (256B-aligned slices) ----
    char* w = (char*)d_ws;
    auto alloc = [&](size_t bytes) -> void* {
        void* p = (void*)w;
        w += (bytes + 255) & ~(size_t)255;
        return p;
    };
    uint4* H0       = (uint4*)alloc((size_t)N * NH * sizeof(uint4));   // 9.6 MB
    uint4* H1       = (uint4*)alloc((size_t)N * NH * sizeof(uint4));   // 9.6 MB
    int* col        = (int*)alloc((size_t)E * sizeof(int));            // 6.4 MB
    int* indeg      = (int*)alloc((size_t)N * sizeof(int));
    int* outdeg     = (int*)alloc((size_t)N * sizeof(int));
    int* row_start  = (int*)alloc((size_t)N * sizeof(int));
    int* cursor     = (int*)alloc((size_t)N * sizeof(int));
    float* snorm    = (float*)alloc((size_t)N * sizeof(float));
    float* dnorm09  = (float*)alloc((size_t)N * sizeof(float));
    int* incl       = (int*)alloc((size_t)N * sizeof(int));
    int* bsum       = (int*)alloc((size_t)nb1 * sizeof(int));

    hipMemsetAsync(indeg, 0, (size_t)N * sizeof(int), stream);
    hipMemsetAsync(outdeg, 0, (size_t)N * sizeof(int), stream);

    const int gridE = (E + 255) / 256;
    const int gridN = (N + 255) / 256;
    const int total = N * NH;
    const int gridT = (total + 255) / 256;

    deg_kernel<<<gridE, 256, 0, stream>>>(src, dst, outdeg, indeg, E);
    scan_chunks<<<nb1, SCAN_BS, 0, stream>>>(indeg, incl, bsum, N);
    scan_sums<<<1, 256, 0, stream>>>(bsum, nb1);
    finalize_kernel<<<gridN, 256, 0, stream>>>(incl, bsum, indeg, outdeg,
                                               row_start, cursor, snorm, dnorm09, N);
    fill_kernel<<<gridE, 256, 0, stream>>>(src, dst, cursor, col, E);

    init_kernel<<<gridT, 256, 0, stream>>>((const float4*)features, snorm, H0, total);

    // step k: fin = H[k&1], fout = H[(k+1)&1]; last writes f32 to d_out
    for (int k = 0; k < KSTEPS; ++k) {
        const uint4* fin = (k & 1) ? (const uint4*)H1 : (const uint4*)H0;
        uint4*       fo  = (k & 1) ? H0 : H1;
        if (k == KSTEPS - 1) {
            step_kernel<1><<<gridT, 256, 0, stream>>>(fin, (const float4*)features,
                                                      row_start, indeg, col, snorm,
                                                      dnorm09, fo, (float4*)out, N);
        } else {
            step_kernel<0><<<gridT, 256, 0, stream>>>(fin, (const float4*)features,
                                                      row_start, indeg, col, snorm,
                                                      dnorm09, fo, nullptr, N);
        }
    }
}